// Round 1
// baseline (1771.822 us; speedup 1.0000x reference)
//
#include <hip/hip_runtime.h>
#include <math.h>

#define BB   4
#define TT   4096
#define DIN  1024
#define DST  2048
#define MM   (BB*TT)   // 16384

// ---------------------------------------------------------------------------
// GEMM1: up[m,s] = (1 - sigmoid(logl[s])) * sum_d u[m,d] * W_in[s,d]
// A = u (M x K, K=DIN, row-major), W = W_in (N x K, N=DST, row-major)  [NT gemm]
// classic 128x128x8 SGEMM, 256 threads, 8x8 per thread
// ---------------------------------------------------------------------------
__global__ __launch_bounds__(256)
void gemm1_kernel(const float* __restrict__ A,
                  const float* __restrict__ W,
                  const float* __restrict__ logl,
                  float* __restrict__ C)
{
    constexpr int K = DIN, N = DST;
    constexpr int BM = 128, BN = 128, BK = 8;
    __shared__ float As[BK][BM];
    __shared__ float Bs[BK][BN];

    const int ntn = N / BN;                 // 16
    const int bn  = blockIdx.x % ntn;
    const int bm  = blockIdx.x / ntn;
    const int tid = threadIdx.x;
    const int tc  = tid & 15;               // 0..15
    const int tr  = tid >> 4;               // 0..15
    const int lrow = tid >> 1;              // 0..127
    const int lcol = (tid & 1) * 4;         // 0 or 4

    const float* Ap = A + (size_t)(bm * BM + lrow) * K + lcol;
    const float* Bp = W + (size_t)(bn * BN + lrow) * K + lcol;

    float acc[8][8];
#pragma unroll
    for (int i = 0; i < 8; ++i)
#pragma unroll
        for (int j = 0; j < 8; ++j) acc[i][j] = 0.f;

    for (int k0 = 0; k0 < K; k0 += BK) {
        float4 av = *reinterpret_cast<const float4*>(Ap + k0);
        float4 bv = *reinterpret_cast<const float4*>(Bp + k0);
        __syncthreads();
        As[lcol + 0][lrow] = av.x; As[lcol + 1][lrow] = av.y;
        As[lcol + 2][lrow] = av.z; As[lcol + 3][lrow] = av.w;
        Bs[lcol + 0][lrow] = bv.x; Bs[lcol + 1][lrow] = bv.y;
        Bs[lcol + 2][lrow] = bv.z; Bs[lcol + 3][lrow] = bv.w;
        __syncthreads();
#pragma unroll
        for (int kk = 0; kk < BK; ++kk) {
            float4 a0 = *reinterpret_cast<const float4*>(&As[kk][tr * 8]);
            float4 a1 = *reinterpret_cast<const float4*>(&As[kk][tr * 8 + 4]);
            float4 b0 = *reinterpret_cast<const float4*>(&Bs[kk][tc * 8]);
            float4 b1 = *reinterpret_cast<const float4*>(&Bs[kk][tc * 8 + 4]);
            float ar[8] = {a0.x, a0.y, a0.z, a0.w, a1.x, a1.y, a1.z, a1.w};
            float br[8] = {b0.x, b0.y, b0.z, b0.w, b1.x, b1.y, b1.z, b1.w};
#pragma unroll
            for (int i = 0; i < 8; ++i)
#pragma unroll
                for (int j = 0; j < 8; ++j)
                    acc[i][j] = fmaf(ar[i], br[j], acc[i][j]);
        }
    }

    // epilogue: scale column s by (1 - lam_s)
    float sc[8];
#pragma unroll
    for (int j = 0; j < 8; ++j) {
        int s = bn * BN + tc * 8 + j;
        float lam = 1.f / (1.f + expf(-logl[s]));
        sc[j] = 1.f - lam;
    }
    float* Cp = C + (size_t)(bm * BM + tr * 8) * N + bn * BN + tc * 8;
#pragma unroll
    for (int i = 0; i < 8; ++i)
#pragma unroll
        for (int j = 0; j < 8; ++j)
            Cp[(size_t)i * N + j] = acc[i][j] * sc[j];
}

// ---------------------------------------------------------------------------
// Scan: x_t = lam * x_{t-1} + up_t  (up already scaled by (1-lam)); in-place.
// One thread per (b, s): 8192 threads.
// ---------------------------------------------------------------------------
__global__ __launch_bounds__(256)
void scan_kernel(float* __restrict__ up, const float* __restrict__ logl)
{
    const int gid = blockIdx.x * 256 + threadIdx.x;   // 0..8191
    const int b = gid >> 11;                           // /2048
    const int s = gid & (DST - 1);
    const float lam = 1.f / (1.f + expf(-logl[s]));
    float x = 0.f;
    float* p = up + (size_t)b * TT * DST + s;
    for (int t = 0; t < TT; t += 8) {
        float v[8];
#pragma unroll
        for (int j = 0; j < 8; ++j)
            v[j] = p[(size_t)(t + j) * DST];
#pragma unroll
        for (int j = 0; j < 8; ++j) {
            x = fmaf(lam, x, v[j]);
            v[j] = x;
        }
#pragma unroll
        for (int j = 0; j < 8; ++j)
            p[(size_t)(t + j) * DST] = v[j];
    }
}

// ---------------------------------------------------------------------------
// GEMM2: y[m,d] = sum_s xs[m,s] * W_out[d,s] + u[m,d] * D[d]
// X = xs (M x K, K=DST), W = W_out (N x K, N=DIN)   [NT gemm]
// ---------------------------------------------------------------------------
__global__ __launch_bounds__(256)
void gemm2_kernel(const float* __restrict__ X,
                  const float* __restrict__ W,
                  const float* __restrict__ U,
                  const float* __restrict__ Dv,
                  float* __restrict__ Y)
{
    constexpr int K = DST, N = DIN;
    constexpr int BM = 128, BN = 128, BK = 8;
    __shared__ float As[BK][BM];
    __shared__ float Bs[BK][BN];

    const int ntn = N / BN;                 // 8
    const int bn  = blockIdx.x % ntn;
    const int bm  = blockIdx.x / ntn;
    const int tid = threadIdx.x;
    const int tc  = tid & 15;
    const int tr  = tid >> 4;
    const int lrow = tid >> 1;
    const int lcol = (tid & 1) * 4;

    const float* Ap = X + (size_t)(bm * BM + lrow) * K + lcol;
    const float* Bp = W + (size_t)(bn * BN + lrow) * K + lcol;

    float acc[8][8];
#pragma unroll
    for (int i = 0; i < 8; ++i)
#pragma unroll
        for (int j = 0; j < 8; ++j) acc[i][j] = 0.f;

    for (int k0 = 0; k0 < K; k0 += BK) {
        float4 av = *reinterpret_cast<const float4*>(Ap + k0);
        float4 bv = *reinterpret_cast<const float4*>(Bp + k0);
        __syncthreads();
        As[lcol + 0][lrow] = av.x; As[lcol + 1][lrow] = av.y;
        As[lcol + 2][lrow] = av.z; As[lcol + 3][lrow] = av.w;
        Bs[lcol + 0][lrow] = bv.x; Bs[lcol + 1][lrow] = bv.y;
        Bs[lcol + 2][lrow] = bv.z; Bs[lcol + 3][lrow] = bv.w;
        __syncthreads();
#pragma unroll
        for (int kk = 0; kk < BK; ++kk) {
            float4 a0 = *reinterpret_cast<const float4*>(&As[kk][tr * 8]);
            float4 a1 = *reinterpret_cast<const float4*>(&As[kk][tr * 8 + 4]);
            float4 b0 = *reinterpret_cast<const float4*>(&Bs[kk][tc * 8]);
            float4 b1 = *reinterpret_cast<const float4*>(&Bs[kk][tc * 8 + 4]);
            float ar[8] = {a0.x, a0.y, a0.z, a0.w, a1.x, a1.y, a1.z, a1.w};
            float br[8] = {b0.x, b0.y, b0.z, b0.w, b1.x, b1.y, b1.z, b1.w};
#pragma unroll
            for (int i = 0; i < 8; ++i)
#pragma unroll
                for (int j = 0; j < 8; ++j)
                    acc[i][j] = fmaf(ar[i], br[j], acc[i][j]);
        }
    }

    // epilogue: + u * D
    float dv[8];
#pragma unroll
    for (int j = 0; j < 8; ++j)
        dv[j] = Dv[bn * BN + tc * 8 + j];

#pragma unroll
    for (int i = 0; i < 8; ++i) {
        const size_t row = (size_t)(bm * BM + tr * 8 + i);
        const float* Up = U + row * N + bn * BN + tc * 8;
        float* Yp = Y + row * N + bn * BN + tc * 8;
#pragma unroll
        for (int j = 0; j < 8; ++j)
            Yp[j] = fmaf(Up[j], dv[j], acc[i][j]);
    }
}

// ---------------------------------------------------------------------------
extern "C" void kernel_launch(void* const* d_in, const int* in_sizes, int n_in,
                              void* d_out, int out_size, void* d_ws, size_t ws_size,
                              hipStream_t stream)
{
    const float* u     = (const float*)d_in[0];   // B,T,DIN
    const float* W_in  = (const float*)d_in[1];   // DST,DIN
    const float* logl  = (const float*)d_in[2];   // DST
    const float* W_out = (const float*)d_in[3];   // DIN,DST
    const float* Dv    = (const float*)d_in[4];   // DIN
    float* y  = (float*)d_out;                    // B,T,DIN
    float* up = (float*)d_ws;                     // M x DST fp32 = 128 MiB scratch

    // GEMM1 + (1-lam) scaling -> ws
    {
        dim3 grid((MM / 128) * (DST / 128));      // 128*16 = 2048
        gemm1_kernel<<<grid, 256, 0, stream>>>(u, W_in, logl, up);
    }
    // sequential scan over T, in-place in ws
    {
        scan_kernel<<<dim3(8192 / 256), 256, 0, stream>>>(up, logl);
    }
    // GEMM2 + u*D -> d_out
    {
        dim3 grid((MM / 128) * (DIN / 128));      // 128*8 = 1024
        gemm2_kernel<<<grid, 256, 0, stream>>>(up, W_out, u, Dv, y);
    }
}

// Round 2
// 319.428 us; speedup vs baseline: 5.5469x; 5.5469x over previous
//
#include <hip/hip_runtime.h>
#include <math.h>

#define BB   4
#define TT   4096
#define DIN  1024
#define DST  2048
#define MM   (BB*TT)     // 16384
#define CHK  32          // scan chunks per sequence
#define CLEN (TT/CHK)    // 128

typedef __bf16 bf16x8 __attribute__((ext_vector_type(8)));
typedef float  f32x4  __attribute__((ext_vector_type(4)));

__device__ __forceinline__ unsigned short f2bf(float f) {
    union { float f; unsigned u; } v; v.f = f;
    unsigned r = v.u + 0x7FFFu + ((v.u >> 16) & 1u);   // RNE
    return (unsigned short)(r >> 16);
}
__device__ __forceinline__ float bf2f(unsigned short h) {
    union { unsigned u; float f; } v; v.u = ((unsigned)h) << 16;
    return v.f;
}
__device__ __forceinline__ float sigm(float x) { return 1.f / (1.f + __expf(-x)); }

// ---------------------------------------------------------------------------
// fp32 -> bf16 conversion, 4 elems/thread
// ---------------------------------------------------------------------------
__global__ __launch_bounds__(256)
void cvt_kernel(const float* __restrict__ in, unsigned short* __restrict__ out, int n4)
{
    int i = blockIdx.x * 256 + threadIdx.x;
    if (i >= n4) return;
    float4 f = reinterpret_cast<const float4*>(in)[i];
    ushort4 o;
    o.x = f2bf(f.x); o.y = f2bf(f.y); o.z = f2bf(f.z); o.w = f2bf(f.w);
    reinterpret_cast<ushort4*>(out)[i] = o;
}

// ---------------------------------------------------------------------------
// bf16 NT MFMA GEMM, 128x128 tile, BK=64, 4 waves, 16x16x32 MFMA (m97 structure)
// C[m,n] = sum_k A[m,k]*B[n,k]   A: MxK row-major, B: NxK row-major, both bf16
// FUSE=false: Obf[m,n] = bf16(acc)            (GEMM1: u_proj)
// FUSE=true : Of[m,n]  = acc + U[m,n]*Dv[n]   (GEMM2: y)
// ---------------------------------------------------------------------------
template<int K, int NB, bool FUSE>
__global__ __launch_bounds__(256)
void gemm_bf16(const unsigned short* __restrict__ A,
               const unsigned short* __restrict__ B,
               unsigned short* __restrict__ Obf,
               float* __restrict__ Of,
               const float* __restrict__ U,
               const float* __restrict__ Dv)
{
    __shared__ unsigned short lA[128 * 64];
    __shared__ unsigned short lB[128 * 64];
    constexpr int N = NB * 128;

    // XCD-aware swizzle (grid % 8 == 0 for both GEMMs -> bijective)
    const int nwg = gridDim.x;
    const int bid = blockIdx.x;
    const int swz = (bid & 7) * (nwg >> 3) + (bid >> 3);
    const int bm = swz / NB, bn = swz % NB;

    const int tid  = threadIdx.x;
    const int lane = tid & 63;
    const int wid  = tid >> 6;          // 0..3
    const int wr   = wid >> 1, wc = wid & 1;
    const int fr   = lane & 15, fq = lane >> 4;

    // staging: thread tid covers 16B = 8 bf16; row=tid/8, col=(tid&7)*8
    const unsigned short* Ag = A + (size_t)(bm * 128 + (tid >> 3)) * K + (tid & 7) * 8;
    const unsigned short* Bg = B + (size_t)(bn * 128 + (tid >> 3)) * K + (tid & 7) * 8;

    f32x4 acc[4][4];
#pragma unroll
    for (int m = 0; m < 4; ++m)
#pragma unroll
        for (int n = 0; n < 4; ++n) {
            acc[m][n][0] = 0.f; acc[m][n][1] = 0.f;
            acc[m][n][2] = 0.f; acc[m][n][3] = 0.f;
        }

    for (int k0 = 0; k0 < K; k0 += 64) {
        __syncthreads();
#pragma unroll
        for (int c = 0; c < 4; ++c) {
            __builtin_amdgcn_global_load_lds(
                (const __attribute__((address_space(1))) void*)(Ag + k0 + (size_t)c * 32 * K),
                (__attribute__((address_space(3))) void*)(&lA[tid * 8 + c * 2048]),
                16, 0, 0);
            __builtin_amdgcn_global_load_lds(
                (const __attribute__((address_space(1))) void*)(Bg + k0 + (size_t)c * 32 * K),
                (__attribute__((address_space(3))) void*)(&lB[tid * 8 + c * 2048]),
                16, 0, 0);
        }
        __syncthreads();   // compiler inserts s_waitcnt vmcnt(0) before barrier
#pragma unroll
        for (int kk = 0; kk < 2; ++kk) {
            bf16x8 af[4], bfv[4];
#pragma unroll
            for (int m = 0; m < 4; ++m)
                af[m] = *reinterpret_cast<const bf16x8*>(
                    &lA[(wr * 64 + m * 16 + fr) * 64 + kk * 32 + fq * 8]);
#pragma unroll
            for (int n = 0; n < 4; ++n)
                bfv[n] = *reinterpret_cast<const bf16x8*>(
                    &lB[(wc * 64 + n * 16 + fr) * 64 + kk * 32 + fq * 8]);
#pragma unroll
            for (int m = 0; m < 4; ++m)
#pragma unroll
                for (int n = 0; n < 4; ++n)
                    acc[m][n] = __builtin_amdgcn_mfma_f32_16x16x32_bf16(
                        af[m], bfv[n], acc[m][n], 0, 0, 0);
        }
    }

    // C/D layout: col = lane&15, row = (lane>>4)*4 + reg   [m89-verified]
    const int row0 = bm * 128 + wr * 64 + fq * 4;
    const int col0 = bn * 128 + wc * 64 + fr;
    if (FUSE) {
#pragma unroll
        for (int n = 0; n < 4; ++n) {
            const int col = col0 + n * 16;
            const float d = Dv[col];
#pragma unroll
            for (int m = 0; m < 4; ++m)
#pragma unroll
                for (int r = 0; r < 4; ++r) {
                    const size_t idx = (size_t)(row0 + m * 16 + r) * N + col;
                    Of[idx] = acc[m][n][r] + U[idx] * d;
                }
        }
    } else {
#pragma unroll
        for (int m = 0; m < 4; ++m)
#pragma unroll
            for (int r = 0; r < 4; ++r) {
                const size_t rowoff = (size_t)(row0 + m * 16 + r) * N;
#pragma unroll
                for (int n = 0; n < 4; ++n)
                    Obf[rowoff + col0 + n * 16] = f2bf(acc[m][n][r]);
            }
    }
}

// ---------------------------------------------------------------------------
// Chunked scan, 3 phases. up is bf16 [B][T][DST] = raw u_proj (unscaled).
// x_t = lam*x_{t-1} + (1-lam)*up_t ; chunk composition: x_end = lam^L*x_in + local
// Each thread handles an s-pair (ushort2 loads).
// ---------------------------------------------------------------------------
__global__ __launch_bounds__(256)
void scan1_kernel(const unsigned short* __restrict__ up,
                  const float* __restrict__ logl,
                  float* __restrict__ fin)
{
    const int gid = blockIdx.x * 256 + threadIdx.x;   // B*CHK*(DST/2)
    const int sp  = gid & (DST / 2 - 1);
    const int bc  = gid >> 10;                         // b*CHK + c
    const int c   = bc & (CHK - 1), b = bc >> 5;
    const int s0  = sp * 2;
    const float lam0 = sigm(logl[s0]),  lam1 = sigm(logl[s0 + 1]);
    const float o0 = 1.f - lam0, o1 = 1.f - lam1;
    const ushort2* p = reinterpret_cast<const ushort2*>(
        up + ((size_t)b * TT + (size_t)c * CLEN) * DST + s0);
    float x0 = 0.f, x1 = 0.f;
    for (int t = 0; t < CLEN; ++t) {
        ushort2 v = p[(size_t)t * (DST / 2)];
        x0 = fmaf(lam0, x0, o0 * bf2f(v.x));
        x1 = fmaf(lam1, x1, o1 * bf2f(v.y));
    }
    reinterpret_cast<float2*>(fin + (size_t)bc * DST + s0)[0] = make_float2(x0, x1);
}

__global__ __launch_bounds__(256)
void scan2_kernel(float* __restrict__ fin, const float* __restrict__ logl)
{
    const int gid = blockIdx.x * 256 + threadIdx.x;   // B*DST
    const int s = gid & (DST - 1), b = gid >> 11;
    const float lam = sigm(logl[s]);
    float lamL = lam;
#pragma unroll
    for (int i = 0; i < 7; ++i) lamL *= lamL;          // lam^128
    float x = 0.f;
    float* f = fin + (size_t)b * CHK * DST + s;
#pragma unroll
    for (int c = 0; c < CHK; ++c) {
        float v = f[(size_t)c * DST];
        f[(size_t)c * DST] = x;                        // exclusive carry-in
        x = fmaf(lamL, x, v);
    }
}

__global__ __launch_bounds__(256)
void scan3_kernel(unsigned short* __restrict__ up,
                  const float* __restrict__ logl,
                  const float* __restrict__ fin)
{
    const int gid = blockIdx.x * 256 + threadIdx.x;
    const int sp  = gid & (DST / 2 - 1);
    const int bc  = gid >> 10;
    const int c   = bc & (CHK - 1), b = bc >> 5;
    const int s0  = sp * 2;
    const float lam0 = sigm(logl[s0]),  lam1 = sigm(logl[s0 + 1]);
    const float o0 = 1.f - lam0, o1 = 1.f - lam1;
    const float2 cv = reinterpret_cast<const float2*>(fin + (size_t)bc * DST + s0)[0];
    float x0 = cv.x, x1 = cv.y;
    ushort2* p = reinterpret_cast<ushort2*>(
        up + ((size_t)b * TT + (size_t)c * CLEN) * DST + s0);
    for (int t = 0; t < CLEN; ++t) {
        ushort2 v = p[(size_t)t * (DST / 2)];
        x0 = fmaf(lam0, x0, o0 * bf2f(v.x));
        x1 = fmaf(lam1, x1, o1 * bf2f(v.y));
        p[(size_t)t * (DST / 2)] = make_ushort2(f2bf(x0), f2bf(x1));
    }
}

// ---------------------------------------------------------------------------
extern "C" void kernel_launch(void* const* d_in, const int* in_sizes, int n_in,
                              void* d_out, int out_size, void* d_ws, size_t ws_size,
                              hipStream_t stream)
{
    const float* u     = (const float*)d_in[0];   // B,T,DIN
    const float* W_in  = (const float*)d_in[1];   // DST,DIN
    const float* logl  = (const float*)d_in[2];   // DST
    const float* W_out = (const float*)d_in[3];   // DIN,DST
    const float* Dv    = (const float*)d_in[4];   // DIN
    float* y = (float*)d_out;

    char* ws = (char*)d_ws;
    unsigned short* uA  = (unsigned short*)(ws);                      // 32 MiB
    unsigned short* wA  = (unsigned short*)(ws + (32ull << 20));      //  4 MiB
    unsigned short* wB  = (unsigned short*)(ws + (36ull << 20));      //  4 MiB
    unsigned short* upb = (unsigned short*)(ws + (40ull << 20));      // 64 MiB
    float*          fin = (float*)(ws + (104ull << 20));              //  1 MiB

    // fp32 -> bf16 conversions
    cvt_kernel<<<(MM * DIN / 4) / 256, 256, 0, stream>>>(u, uA, MM * DIN / 4);
    cvt_kernel<<<(DST * DIN / 4) / 256, 256, 0, stream>>>(W_in, wA, DST * DIN / 4);
    cvt_kernel<<<(DIN * DST / 4) / 256, 256, 0, stream>>>(W_out, wB, DIN * DST / 4);

    // GEMM1: u_proj (raw, unscaled) -> upb bf16
    gemm_bf16<DIN, DST / 128, false><<<(MM / 128) * (DST / 128), 256, 0, stream>>>(
        uA, wA, upb, nullptr, nullptr, nullptr);

    // chunked diagonal scan, in place on upb
    scan1_kernel<<<(BB * CHK * DST / 2) / 256, 256, 0, stream>>>(upb, logl, fin);
    scan2_kernel<<<(BB * DST) / 256, 256, 0, stream>>>(fin, logl);
    scan3_kernel<<<(BB * CHK * DST / 2) / 256, 256, 0, stream>>>(upb, logl, fin);

    // GEMM2: y = xs @ W_out^T + u*D
    gemm_bf16<DST, DIN / 128, true><<<(MM / 128) * (DIN / 128), 256, 0, stream>>>(
        upb, wB, nullptr, y, u, Dv);
}

// Round 3
// 210.369 us; speedup vs baseline: 8.4225x; 1.5184x over previous
//
#include <hip/hip_runtime.h>
#include <math.h>

#define BB   4
#define TT   4096
#define DIN  1024
#define DST  2048
#define MM   (BB*TT)     // 16384
#define CHK  32          // scan chunks per sequence
#define CLEN (TT/CHK)    // 128

typedef __bf16 bf16x8 __attribute__((ext_vector_type(8)));
typedef float  f32x4  __attribute__((ext_vector_type(4)));

__device__ __forceinline__ unsigned short f2bf(float f) {
    union { float f; unsigned u; } v; v.f = f;
    unsigned r = v.u + 0x7FFFu + ((v.u >> 16) & 1u);   // RNE
    return (unsigned short)(r >> 16);
}
__device__ __forceinline__ float bf2f(unsigned short h) {
    union { unsigned u; float f; } v; v.u = ((unsigned)h) << 16;
    return v.f;
}
__device__ __forceinline__ float sigm(float x) { return 1.f / (1.f + __expf(-x)); }

// ---------------------------------------------------------------------------
// fp32 -> bf16 conversion, 4 elems/thread
// ---------------------------------------------------------------------------
__global__ __launch_bounds__(256)
void cvt_kernel(const float* __restrict__ in, unsigned short* __restrict__ out, int n4)
{
    int i = blockIdx.x * 256 + threadIdx.x;
    if (i >= n4) return;
    float4 f = reinterpret_cast<const float4*>(in)[i];
    ushort4 o;
    o.x = f2bf(f.x); o.y = f2bf(f.y); o.z = f2bf(f.z); o.w = f2bf(f.w);
    reinterpret_cast<ushort4*>(out)[i] = o;
}

// ---------------------------------------------------------------------------
// Pipelined bf16 NT MFMA GEMM (T2+T3+T4+T5 stack):
//   BM=256, BN=128, BK=64, 512 threads = 8 waves (4M x 2N), 64x64 per wave.
//   3-deep circular LDS K-tile buffer (A 32KB + B 16KB per tile = 144 KiB),
//   prefetch depth 2, counted vmcnt(6) (6 staging loads/wave/K-tile),
//   st-swizzle col ^= (row&7)<<3 on both stage-source and ds_read.
// C[m,n] = sum_k A[m,k]*B[n,k];  A: MxK, B: NxK, both bf16 row-major.
// FUSE=false: Obf = bf16(acc)             (GEMM1: u_proj)
// FUSE=true : Of  = acc + U*Dv[col]       (GEMM2: y)
// ---------------------------------------------------------------------------
#define BUF_E 24576   // elems per K-tile buffer: A 16384 + B 8192

template<int K, int NB, bool FUSE>
__global__ __launch_bounds__(512, 2)
void gemm_pipe(const unsigned short* __restrict__ A,
               const unsigned short* __restrict__ B,
               unsigned short* __restrict__ Obf,
               float* __restrict__ Of,
               const float* __restrict__ U,
               const float* __restrict__ Dv)
{
    constexpr int N  = NB * 128;
    constexpr int NT = K / 64;
    __shared__ __align__(16) unsigned short lds[3 * BUF_E];   // 144 KiB

    // XCD-aware bijective swizzle (nwg % 8 == 0 for both GEMMs)
    const int nwg = gridDim.x;
    const int bid = blockIdx.x;
    const int swz = (bid & 7) * (nwg >> 3) + (bid >> 3);
    const int bm = swz / NB, bn = swz % NB;

    const int tid  = threadIdx.x;
    const int lane = tid & 63;
    const int wid  = tid >> 6;          // 0..7
    const int wr   = wid >> 1;          // 0..3  (64-row band of 256)
    const int wc   = wid & 1;           // 0..1  (64-col band of 128)
    const int fr   = lane & 15, fq = lane >> 4;

    // --- staging: linear LDS dest, pre-swizzled global source column ---
    const int srow = tid >> 3;                                  // 0..63
    const int scol = ((tid & 7) << 3) ^ ((srow & 7) << 3);      // swizzled col
    const unsigned short* Ag = A + (size_t)(bm * 256 + srow) * K + scol;
    const unsigned short* Bg = B + (size_t)(bn * 128 + srow) * K + scol;
    const int ldsA = tid * 8;            // + r*4096 (rounds 0..3)
    const int ldsB = 16384 + tid * 8;    // + r*4096 (rounds 0..1)

    auto stageA = [&](int r, int kof, int buf) {
        __builtin_amdgcn_global_load_lds(
            (const __attribute__((address_space(1))) void*)(Ag + kof + (size_t)r * 64 * K),
            (__attribute__((address_space(3))) void*)(&lds[buf + ldsA + r * 4096]),
            16, 0, 0);
    };
    auto stageB = [&](int r, int kof, int buf) {
        __builtin_amdgcn_global_load_lds(
            (const __attribute__((address_space(1))) void*)(Bg + kof + (size_t)r * 64 * K),
            (__attribute__((address_space(3))) void*)(&lds[buf + ldsB + r * 4096]),
            16, 0, 0);
    };

    // --- frag read offsets (swizzle const per thread: row&7 == fr&7) ---
    const int sx    = (fr & 7) << 3;
    const int ac0   = (fq * 8) ^ sx;            // kk=0 col'
    const int ac1   = (32 + fq * 8) ^ sx;       // kk=1 col'
    const int aBase = (wr * 64 + fr) * 64;             // + m*1024 + ac
    const int bBase = 16384 + (wc * 64 + fr) * 64;     // + n*1024 + ac

    f32x4 acc[4][4];
#pragma unroll
    for (int m = 0; m < 4; ++m)
#pragma unroll
        for (int n = 0; n < 4; ++n) {
            acc[m][n][0] = 0.f; acc[m][n][1] = 0.f;
            acc[m][n][2] = 0.f; acc[m][n][3] = 0.f;
        }

    // --- prologue: stage K-tiles 0 and 1 ---
#pragma unroll
    for (int r = 0; r < 4; ++r) stageA(r, 0, 0);
    stageB(0, 0, 0); stageB(1, 0, 0);
#pragma unroll
    for (int r = 0; r < 4; ++r) stageA(r, 64, BUF_E);
    stageB(0, 64, BUF_E); stageB(1, 64, BUF_E);

    int cur = 0, nx1 = BUF_E, nx2 = 2 * BUF_E;

    for (int t = 0; t < NT; ++t) {
        // wait for tile t's 6 loads; keep t+1's 6 in flight (counted vmcnt)
        if (t + 1 < NT) asm volatile("s_waitcnt vmcnt(6)" ::: "memory");
        else            asm volatile("s_waitcnt vmcnt(0)" ::: "memory");
        __builtin_amdgcn_s_barrier();
        __builtin_amdgcn_sched_barrier(0);

        const int  kof = (t + 2) * 64;
        const bool st  = (t + 2) < NT;

        // ================= phase 0 (kk=0) =================
        {
            bf16x8 af[4], bfv[4];
#pragma unroll
            for (int m = 0; m < 4; ++m)
                af[m] = *reinterpret_cast<const bf16x8*>(&lds[cur + aBase + m * 1024 + ac0]);
#pragma unroll
            for (int n = 0; n < 4; ++n)
                bfv[n] = *reinterpret_cast<const bf16x8*>(&lds[cur + bBase + n * 1024 + ac0]);
            if (st) { stageA(0, kof, nx2); stageA(1, kof, nx2); stageA(2, kof, nx2); }
            __builtin_amdgcn_s_barrier();
            asm volatile("s_waitcnt lgkmcnt(0)" ::: "memory");
            __builtin_amdgcn_sched_barrier(0);
            __builtin_amdgcn_s_setprio(1);
#pragma unroll
            for (int m = 0; m < 4; ++m)
#pragma unroll
                for (int n = 0; n < 4; ++n)
                    acc[m][n] = __builtin_amdgcn_mfma_f32_16x16x32_bf16(
                        af[m], bfv[n], acc[m][n], 0, 0, 0);
            __builtin_amdgcn_s_setprio(0);
            __builtin_amdgcn_s_barrier();
        }
        // ================= phase 1 (kk=1) =================
        {
            bf16x8 af[4], bfv[4];
#pragma unroll
            for (int m = 0; m < 4; ++m)
                af[m] = *reinterpret_cast<const bf16x8*>(&lds[cur + aBase + m * 1024 + ac1]);
#pragma unroll
            for (int n = 0; n < 4; ++n)
                bfv[n] = *reinterpret_cast<const bf16x8*>(&lds[cur + bBase + n * 1024 + ac1]);
            if (st) { stageA(3, kof, nx2); stageB(0, kof, nx2); stageB(1, kof, nx2); }
            __builtin_amdgcn_s_barrier();
            asm volatile("s_waitcnt lgkmcnt(0)" ::: "memory");
            __builtin_amdgcn_sched_barrier(0);
            __builtin_amdgcn_s_setprio(1);
#pragma unroll
            for (int m = 0; m < 4; ++m)
#pragma unroll
                for (int n = 0; n < 4; ++n)
                    acc[m][n] = __builtin_amdgcn_mfma_f32_16x16x32_bf16(
                        af[m], bfv[n], acc[m][n], 0, 0, 0);
            __builtin_amdgcn_s_setprio(0);
        }
        // rotate circular buffers
        int tmp = cur; cur = nx1; nx1 = nx2; nx2 = tmp;
    }

    // --- epilogue.  C/D layout: col = lane&15, row = fq*4 + reg ---
    const int row0 = bm * 256 + wr * 64 + fq * 4;
    const int col0 = bn * 128 + wc * 64 + fr;
    if (FUSE) {
#pragma unroll
        for (int n = 0; n < 4; ++n) {
            const int col = col0 + n * 16;
            const float d = Dv[col];
#pragma unroll
            for (int m = 0; m < 4; ++m)
#pragma unroll
                for (int r = 0; r < 4; ++r) {
                    const size_t idx = (size_t)(row0 + m * 16 + r) * N + col;
                    Of[idx] = acc[m][n][r] + U[idx] * d;
                }
        }
    } else {
#pragma unroll
        for (int m = 0; m < 4; ++m)
#pragma unroll
            for (int r = 0; r < 4; ++r) {
                const size_t rowoff = (size_t)(row0 + m * 16 + r) * N;
#pragma unroll
                for (int n = 0; n < 4; ++n)
                    Obf[rowoff + col0 + n * 16] = f2bf(acc[m][n][r]);
            }
    }
}

// ---------------------------------------------------------------------------
// Chunked scan, 3 phases. up is bf16 [B][T][DST] = raw u_proj (unscaled).
// ---------------------------------------------------------------------------
__global__ __launch_bounds__(256)
void scan1_kernel(const unsigned short* __restrict__ up,
                  const float* __restrict__ logl,
                  float* __restrict__ fin)
{
    const int gid = blockIdx.x * 256 + threadIdx.x;   // B*CHK*(DST/2)
    const int sp  = gid & (DST / 2 - 1);
    const int bc  = gid >> 10;                         // b*CHK + c
    const int c   = bc & (CHK - 1), b = bc >> 5;
    const int s0  = sp * 2;
    const float lam0 = sigm(logl[s0]),  lam1 = sigm(logl[s0 + 1]);
    const float o0 = 1.f - lam0, o1 = 1.f - lam1;
    const ushort2* p = reinterpret_cast<const ushort2*>(
        up + ((size_t)b * TT + (size_t)c * CLEN) * DST + s0);
    float x0 = 0.f, x1 = 0.f;
    for (int t = 0; t < CLEN; ++t) {
        ushort2 v = p[(size_t)t * (DST / 2)];
        x0 = fmaf(lam0, x0, o0 * bf2f(v.x));
        x1 = fmaf(lam1, x1, o1 * bf2f(v.y));
    }
    reinterpret_cast<float2*>(fin + (size_t)bc * DST + s0)[0] = make_float2(x0, x1);
}

__global__ __launch_bounds__(256)
void scan2_kernel(float* __restrict__ fin, const float* __restrict__ logl)
{
    const int gid = blockIdx.x * 256 + threadIdx.x;   // B*DST
    const int s = gid & (DST - 1), b = gid >> 11;
    const float lam = sigm(logl[s]);
    float lamL = lam;
#pragma unroll
    for (int i = 0; i < 7; ++i) lamL *= lamL;          // lam^128
    float x = 0.f;
    float* f = fin + (size_t)b * CHK * DST + s;
#pragma unroll
    for (int c = 0; c < CHK; ++c) {
        float v = f[(size_t)c * DST];
        f[(size_t)c * DST] = x;                        // exclusive carry-in
        x = fmaf(lamL, x, v);
    }
}

__global__ __launch_bounds__(256)
void scan3_kernel(unsigned short* __restrict__ up,
                  const float* __restrict__ logl,
                  const float* __restrict__ fin)
{
    const int gid = blockIdx.x * 256 + threadIdx.x;
    const int sp  = gid & (DST / 2 - 1);
    const int bc  = gid >> 10;
    const int c   = bc & (CHK - 1), b = bc >> 5;
    const int s0  = sp * 2;
    const float lam0 = sigm(logl[s0]),  lam1 = sigm(logl[s0 + 1]);
    const float o0 = 1.f - lam0, o1 = 1.f - lam1;
    const float2 cv = reinterpret_cast<const float2*>(fin + (size_t)bc * DST + s0)[0];
    float x0 = cv.x, x1 = cv.y;
    ushort2* p = reinterpret_cast<ushort2*>(
        up + ((size_t)b * TT + (size_t)c * CLEN) * DST + s0);
    for (int t = 0; t < CLEN; ++t) {
        ushort2 v = p[(size_t)t * (DST / 2)];
        x0 = fmaf(lam0, x0, o0 * bf2f(v.x));
        x1 = fmaf(lam1, x1, o1 * bf2f(v.y));
        p[(size_t)t * (DST / 2)] = make_ushort2(f2bf(x0), f2bf(x1));
    }
}

// ---------------------------------------------------------------------------
extern "C" void kernel_launch(void* const* d_in, const int* in_sizes, int n_in,
                              void* d_out, int out_size, void* d_ws, size_t ws_size,
                              hipStream_t stream)
{
    const float* u     = (const float*)d_in[0];   // B,T,DIN
    const float* W_in  = (const float*)d_in[1];   // DST,DIN
    const float* logl  = (const float*)d_in[2];   // DST
    const float* W_out = (const float*)d_in[3];   // DIN,DST
    const float* Dv    = (const float*)d_in[4];   // DIN
    float* y = (float*)d_out;

    char* ws = (char*)d_ws;
    unsigned short* uA  = (unsigned short*)(ws);                      // 32 MiB
    unsigned short* wA  = (unsigned short*)(ws + (32ull << 20));      //  4 MiB
    unsigned short* wB  = (unsigned short*)(ws + (36ull << 20));      //  4 MiB
    unsigned short* upb = (unsigned short*)(ws + (40ull << 20));      // 64 MiB
    float*          fin = (float*)(ws + (104ull << 20));              //  1 MiB

    // fp32 -> bf16 conversions
    cvt_kernel<<<(MM * DIN / 4) / 256, 256, 0, stream>>>(u, uA, MM * DIN / 4);
    cvt_kernel<<<(DST * DIN / 4) / 256, 256, 0, stream>>>(W_in, wA, DST * DIN / 4);
    cvt_kernel<<<(DIN * DST / 4) / 256, 256, 0, stream>>>(W_out, wB, DIN * DST / 4);

    // GEMM1: u_proj (raw, unscaled) -> upb bf16
    gemm_pipe<DIN, DST / 128, false><<<(MM / 256) * (DST / 128), 512, 0, stream>>>(
        uA, wA, upb, nullptr, nullptr, nullptr);

    // chunked diagonal scan, in place on upb
    scan1_kernel<<<(BB * CHK * DST / 2) / 256, 256, 0, stream>>>(upb, logl, fin);
    scan2_kernel<<<(BB * DST) / 256, 256, 0, stream>>>(fin, logl);
    scan3_kernel<<<(BB * CHK * DST / 2) / 256, 256, 0, stream>>>(upb, logl, fin);

    // GEMM2: y = xs @ W_out^T + u*D
    gemm_pipe<DST, DIN / 128, true><<<(MM / 256) * (DIN / 128), 512, 0, stream>>>(
        upb, wB, nullptr, y, u, Dv);
}